// Round 15
// baseline (183.281 us; speedup 1.0000x reference)
//
#include <hip/hip_runtime.h>
#include <limits.h>
#include <stdint.h>

#define ALPHA 0.2f
#define HALFA 0.1f
static constexpr int N = 8192;
static constexpr int D = 128;
static constexpr int C = 512;
static constexpr int BT = 128;                    // tile edge (points per tile)
static constexpr int GR = D / 8;                  // 16 granules (half8) per row
static constexpr int SL = BT + 1;                 // padded row count per granule
static constexpr int MAXG = 48;                   // e-list capacity (mean 16, 8 sigma)
static constexpr int NB = N / BT;                 // 64 row/col panels
static constexpr int NSP = NB / 2;                // 32 superpanels
static constexpr int SPB = 16;                    // walker lanes per superpanel
static constexpr int GRID = 512;                  // 2/CU exact -> all blocks co-resident

// Sentinels: EPAD must differ from DMASK (R9 lesson): |EPAD-DMASK| >= HALFA.
#define DMASK 3.0e38f
#define EPAD  1.0e37f

using half8    = __attribute__((ext_vector_type(8))) _Float16;
using floatx16 = __attribute__((ext_vector_type(16))) float;

__device__ __forceinline__ floatx16 zerov() { floatx16 v = {0.f}; return v; }

// superpanel k: tiles 0..lenA-1 are (br=k, bc=k+t); rest are (br=63-k, bc=63-k+t-lenA)
__device__ __forceinline__ void dec_sp(int k, int t, int lenA, int& br, int& bc) {
    if (t < lenA) { br = k;      bc = k + t; }
    else          { br = 63 - k; bc = 63 - k + (t - lenA); }
}

// Manual grid barrier: all GRID blocks are co-resident by construction (2/CU exact,
// resource-checked), so a counted spin cannot deadlock. Device-scope atomics +
// __threadfence provide the cross-XCD release/acquire (guide §6 G16).
__device__ __forceinline__ void grid_barrier(int* bar) {
    __syncthreads();
    if (threadIdx.x == 0) {
        __threadfence();   // release: make this block's global writes visible
        __hip_atomic_fetch_add(bar, 1, __ATOMIC_ACQ_REL, __HIP_MEMORY_SCOPE_AGENT);
        while (__hip_atomic_load(bar, __ATOMIC_ACQUIRE, __HIP_MEMORY_SCOPE_AGENT) < GRID)
            __builtin_amdgcn_s_sleep(8);
        __threadfence();   // acquire: discard stale cached lines
    }
    __syncthreads();
}

// ---- k_all: fused prep (A1/A2) + R12-proven main body (B) -----------------------------
// __launch_bounds__(512,2): proven no-spill (~60-64 VGPR); do NOT tighten (R4/R6).

__launch_bounds__(512, 2)
__global__ void k_all(const float* __restrict__ x, const int* __restrict__ labels,
                      _Float16* __restrict__ xh, float* __restrict__ sq,
                      unsigned* __restrict__ anchor_u, float* __restrict__ ap,
                      int* __restrict__ ecnt, float* __restrict__ egrid,
                      int* __restrict__ bars, float* __restrict__ out) {
    __shared__ __align__(16) _Float16 BsH[GR * SL * 8];   // 33024 B, K-major [granule][row]
    __shared__ __align__(16) float sge[64 * MAXG];        // 12288 B e-lists
    __shared__ float4 rowE[BT];
    __shared__ float4 colE[2][BT];
    __shared__ int   sArow[64];
    __shared__ float sSqA[64];
    __shared__ int   sCnt[64];
    __shared__ float wsum[8];
    half8* Bs = (half8*)BsH;

    const int tid = threadIdx.x;
    const int lane = tid & 63, w = tid >> 6;
    const int m = lane & 31, q = lane >> 5;
    const int sg = tid & 15, sr0 = tid >> 4;   // staging: granule, row base
    float local = 0.f;
    int cnt = 0;                                // hinge slots evaluated (for +h*cnt)

    const int b = blockIdx.x;

    // ================= phase A1: convert 16 rows, sq, anchor atomicMin, ecnt zero ======
    {
        if (tid == 0) { ecnt[b] = 0; if (b == 0) out[0] = 0.f; }
        const int rl = tid >> 5, l32 = tid & 31;    // 32 threads per row
        const int r = b * 16 + rl;
        float4 v = *((const float4*)(x + (size_t)r * D) + l32);
        union { _Float16 h[4]; uint2 u; } cv;
        cv.h[0] = (_Float16)v.x; cv.h[1] = (_Float16)v.y;
        cv.h[2] = (_Float16)v.z; cv.h[3] = (_Float16)v.w;
        *((uint2*)(xh + (size_t)r * D) + l32) = cv.u;
        float ss = v.x*v.x + v.y*v.y + v.z*v.z + v.w*v.w;
        ss += __shfl_xor(ss, 1); ss += __shfl_xor(ss, 2); ss += __shfl_xor(ss, 4);
        ss += __shfl_xor(ss, 8); ss += __shfl_xor(ss, 16);
        if (l32 == 0) {
            sq[r] = ss;
            atomicMin(&anchor_u[labels[r]], (unsigned)r);   // anchor_u pre-memset 0xFF
        }
    }
    grid_barrier(&bars[0]);

    // ================= phase A2: ap (fp16-rounded dot, fp32 sq) + egrid append =========
    {
        const int rl = tid >> 5, l32 = tid & 31;
        const int r = b * 16 + rl;
        const int lab = labels[r];
        const int a = (int)anchor_u[lab];           // label present by construction
        union { uint2 u; _Float16 h[4]; } ca, cr;
        ca.u = *((const uint2*)(xh + (size_t)a * D) + l32);
        cr.u = *((const uint2*)(xh + (size_t)r * D) + l32);
        float dot = 0.f;
#pragma unroll
        for (int e = 0; e < 4; ++e) dot = fmaf((float)ca.h[e], (float)cr.h[e], dot);
        dot += __shfl_xor(dot, 1); dot += __shfl_xor(dot, 2); dot += __shfl_xor(dot, 4);
        dot += __shfl_xor(dot, 8); dot += __shfl_xor(dot, 16);
        if (l32 == 0) {
            float apv = sq[a] + sq[r] - 2.f * dot;
            ap[r] = apv;
            if (r != a) {
                int slot = atomicAdd(&ecnt[lab], 1);
                if (slot < MAXG) egrid[(size_t)lab * MAXG + slot] = apv + HALFA;
            }
        }
    }
    grid_barrier(&bars[1]);

    // ================= phase B: R12 k_main body (verbatim) =============================
    const int* anchor = (const int*)anchor_u;       // absent class = -1 (0xFFFFFFFF)
    const int c0 = (b >> 6) * 64, j1 = (b & 63) * BT;
    const int kk_sp = b >> 4, p = b & 15;
    const int lenA = 64 - kk_sp;

    half8 af[8], breg[4];
    floatx16 acc = zerov();

    // ---- phase 0: term1 meta + EPAD-masked e-list copy + B prefetch ----
    if (tid < 64) {
        int c = c0 + tid;
        int a = anchor[c];
        int ar = (a < 0) ? 0 : a;          // dummy (absent class has cnt 0)
        sArow[tid] = ar;
        sSqA[tid] = sq[ar];
        int n = ecnt[c];
        sCnt[tid] = (n > MAXG) ? MAXG : n;
    }
    {   // e-list copy; pads (uninitialized in egrid) forced to EPAD
        const float4* srcv = (const float4*)(egrid + (size_t)c0 * MAXG);
        float4* dstv = (float4*)sge;
#pragma unroll
        for (int rep = 0; rep < 2; ++rep) {
            int idx = tid + rep * 512;
            if (idx < 64 * (MAXG / 4)) {
                int cls = idx / (MAXG / 4);
                int sb = (idx % (MAXG / 4)) * 4;
                int n = ecnt[c0 + cls]; n = (n > MAXG) ? MAXG : n;
                float4 v = srcv[idx];
                v.x = (sb + 0 < n) ? v.x : EPAD;
                v.y = (sb + 1 < n) ? v.y : EPAD;
                v.z = (sb + 2 < n) ? v.z : EPAD;
                v.w = (sb + 3 < n) ? v.w : EPAD;
                dstv[idx] = v;
            }
        }
    }
#pragma unroll
    for (int i = 0; i < 4; ++i)
        breg[i] = *((const half8*)(xh + (size_t)(j1 + sr0 + 32 * i) * D) + sg);
    if (tid < BT) {
        int j = j1 + tid;
        colE[0][tid] = make_float4(sq[j], __int_as_float(labels[j]), 0.f, 0.f);
    }
    __syncthreads();

    // ---- phase 1: term1 MFMA ----
    {   // gathered anchor rows; 2 row-groups x 4 col-groups
        int arow = sArow[(w >> 2) * 32 + m];
        const half8* aptr = (const half8*)(xh + (size_t)arow * D) + q;
#pragma unroll
        for (int k = 0; k < 8; ++k) af[k] = aptr[2 * k];
    }
#pragma unroll
    for (int i = 0; i < 4; ++i)
        Bs[sg * SL + sr0 + 32 * i] = breg[i];
    __syncthreads();

#pragma unroll
    for (int k = 0; k < 8; ++k) {
        half8 b0 = Bs[(2 * k + q) * SL + (w & 3) * 32 + m];
        acc = __builtin_amdgcn_mfma_f32_32x32x16_f16(af[k], b0, acc, 0, 0, 0);
    }

    // ---- phase 2: prefetch first term2 tile (hides under epilogue) ----
    int br0, bc0;
    dec_sp(kk_sp, p, lenA, br0, bc0);
    {
        const half8* aptr = (const half8*)(xh + (size_t)(br0 * BT + (w >> 1) * 32 + m) * D) + q;
#pragma unroll
        for (int k = 0; k < 8; ++k) af[k] = aptr[2 * k];   // af dead after term1 MFMA
#pragma unroll
        for (int i = 0; i < 4; ++i)
            breg[i] = *((const half8*)(xh + (size_t)(bc0 * BT + sr0 + 32 * i) * D) + sg);
        if (tid < BT) {
            int i = br0 * BT + tid;
            int li = labels[i]; int a = anchor[li];
            float sqi = sq[i];
            float e2 = (i == a) ? -1e30f : ap[i] + HALFA - sqi;
            rowE[tid] = make_float4(e2, __int_as_float(li), sqi, 0.f);
        } else if (tid < 2 * BT) {
            int j = bc0 * BT + tid - BT;
            int lj = labels[j]; int a = anchor[lj];
            float sqj = sq[j];
            float e2 = (j == a) ? -1e30f : ap[j] + HALFA - sqj;
            colE[1][tid - BT] = make_float4(e2, __int_as_float(lj), sqj, 0.f);
        }
    }

    // ---- phase 3: term1 hinge epilogue (R12's proven 4-wide loop) ----
    __builtin_amdgcn_s_setprio(1);
    {
        float4 cj = colE[0][(w & 3) * 32 + m];
        float sqj = cj.x; int labj = __float_as_int(cj.y);
#pragma unroll
        for (int rr = 0; rr < 16; ++rr) {
            int row = (w >> 2) * 32 + (rr & 3) + 8 * (rr >> 2) + 4 * q;
            float Dv = fmaf(-2.f, acc[rr], sSqA[row] + sqj);
            Dv = (labj != c0 + row) ? Dv : DMASK;         // fold label mask into base
            int nf = (sCnt[row] + 3) & ~3;
            cnt += nf;
            for (int gb = 0; gb < nf; gb += 4) {
                float4 ev = *(const float4*)&sge[row * MAXG + gb];
                float u;
                u = ev.x - Dv; local += (__builtin_fabsf(u) < HALFA) ? u : -HALFA;
                u = ev.y - Dv; local += (__builtin_fabsf(u) < HALFA) ? u : -HALFA;
                u = ev.z - Dv; local += (__builtin_fabsf(u) < HALFA) ? u : -HALFA;
                u = ev.w - Dv; local += (__builtin_fabsf(u) < HALFA) ? u : -HALFA;
            }
        }
    }
    __builtin_amdgcn_s_setprio(0);
    __syncthreads();   // rowE/colE[1] ready; Bs free for the walker

    // ---- phase 4: term2 superpanel walker ----
    {
        const int wr = w >> 1, wc = w & 1;     // 4 row-groups x 2 col-groups
        int cbuf = 1, cur_br = br0;

        for (int t = p; t < 65; t += SPB) {
            int br, bc; dec_sp(kk_sp, t, lenA, br, bc);
            const int i0 = br * BT;
            const bool diag = (br == bc);

            if (br != cur_br) {                 // at most one seam per block
                cur_br = br;
                const half8* aptr = (const half8*)(xh + (size_t)(i0 + wr * 32 + m) * D) + q;
#pragma unroll
                for (int k8 = 0; k8 < 8; ++k8) af[k8] = aptr[2 * k8];
                if (tid < BT) {
                    int i = i0 + tid;
                    int li = labels[i]; int a = anchor[li];
                    float sqi = sq[i];
                    float e2 = (i == a) ? -1e30f : ap[i] + HALFA - sqi;
                    rowE[tid] = make_float4(e2, __int_as_float(li), sqi, 0.f);
                }
            }

#pragma unroll
            for (int i = 0; i < 4; ++i)
                Bs[sg * SL + sr0 + 32 * i] = breg[i];
            __syncthreads();

            if (t + SPB < 65) {                 // prefetch next tile
                int brn, bcn; dec_sp(kk_sp, t + SPB, lenA, brn, bcn);
                int j0n = bcn * BT;
#pragma unroll
                for (int i = 0; i < 4; ++i)
                    breg[i] = *((const half8*)(xh + (size_t)(j0n + sr0 + 32 * i) * D) + sg);
                if (tid < BT) {
                    int j = j0n + tid;
                    int lj = labels[j]; int a = anchor[lj];
                    float sqj = sq[j];
                    float e2 = (j == a) ? -1e30f : ap[j] + HALFA - sqj;
                    colE[cbuf ^ 1][tid] = make_float4(e2, __int_as_float(lj), sqj, 0.f);
                }
            }

            __builtin_amdgcn_s_setprio(1);
            floatx16 acc0 = zerov(), acc1 = zerov();
#pragma unroll
            for (int k8 = 0; k8 < 8; ++k8) {
                half8 b0 = Bs[(2 * k8 + q) * SL + wc * 64 + m];
                half8 b1 = Bs[(2 * k8 + q) * SL + wc * 64 + 32 + m];
                acc0 = __builtin_amdgcn_mfma_f32_32x32x16_f16(af[k8], b0, acc0, 0, 0, 0);
                acc1 = __builtin_amdgcn_mfma_f32_32x32x16_f16(af[k8], b1, acc1, 0, 0, 0);
            }

            float sqjv[2], e2j[2]; int labj[2];
            { float4 cj = colE[cbuf][wc * 64 + m];      e2j[0] = cj.x; labj[0] = __float_as_int(cj.y); sqjv[0] = cj.z; }
            { float4 cj = colE[cbuf][wc * 64 + 32 + m]; e2j[1] = cj.x; labj[1] = __float_as_int(cj.y); sqjv[1] = cj.z; }

#pragma unroll
            for (int rr = 0; rr < 16; ++rr) {
                int row = wr * 32 + (rr & 3) + 8 * (rr >> 2) + 4 * q;
                float4 re = rowE[row];
                float e2i = re.x, sqi = re.z;
                int labi = __float_as_int(re.y);
#pragma unroll
                for (int tn = 0; tn < 2; ++tn) {
                    float dot = (tn == 0) ? acc0[rr] : acc1[rr];
                    bool ne = (labi != labj[tn]);
                    float u2 = fmaf(2.f, dot, e2i - sqjv[tn]);
                    local += (ne & (__builtin_fabsf(u2) < HALFA)) ? u2 : -HALFA;
                    if (!diag) {
                        float u2b = fmaf(2.f, dot, e2j[tn] - sqi);
                        local += (ne & (__builtin_fabsf(u2b) < HALFA)) ? u2b : -HALFA;
                    }
                }
            }
            __builtin_amdgcn_s_setprio(0);
            cnt += diag ? 32 : 64;
            cbuf ^= 1;
            __syncthreads();
        }
    }

    // compensation for the -HALFA branchless accumulation, then block reduce
    local += HALFA * (float)cnt;
#pragma unroll
    for (int off = 32; off; off >>= 1) local += __shfl_down(local, off);
    if (lane == 0) wsum[w] = local;
    __syncthreads();
    if (tid == 0) {
        float s = 0.f;
#pragma unroll
        for (int i = 0; i < 8; ++i) s += wsum[i];
        atomicAdd(out, s);
    }
}

// ---------------- launch ----------------

extern "C" void kernel_launch(void* const* d_in, const int* in_sizes, int n_in,
                              void* d_out, int out_size, void* d_ws, size_t ws_size,
                              hipStream_t stream) {
    const float* x = (const float*)d_in[0];
    const int* labels = (const int*)d_in[1];
    float* out = (float*)d_out;

    char* p = (char*)d_ws;
    unsigned* anchor_u = (unsigned*)p; p += C * 4;
    float* sq = (float*)p;             p += N * 4;
    float* ap = (float*)p;             p += N * 4;
    int* ecnt = (int*)p;               p += C * 4;
    float* egrid = (float*)p;          p += (size_t)C * MAXG * 4;
    int* bars = (int*)p;               p += 2 * 4;
    p = (char*)(((uintptr_t)p + 255) & ~(uintptr_t)255);
    _Float16* xh = (_Float16*)p;       // N*D*2 = 2 MB

    // anchor init: 0xFF = UINT_MAX (unsigned atomicMin); barrier counters zeroed;
    // ecnt zeroed in-kernel (A1); egrid pads masked in-kernel (phase 0).
    hipMemsetAsync(anchor_u, 0xFF, C * 4, stream);
    hipMemsetAsync(bars, 0, 2 * 4, stream);
    k_all<<<GRID, 512, 0, stream>>>(x, labels, xh, sq, anchor_u, ap, ecnt, egrid,
                                    bars, out);
}

// Round 16
// 109.877 us; speedup vs baseline: 1.6681x; 1.6681x over previous
//
#include <hip/hip_runtime.h>
#include <limits.h>
#include <stdint.h>

#define ALPHA 0.2f
#define HALFA 0.1f
static constexpr int N = 8192;
static constexpr int D = 128;
static constexpr int C = 512;
static constexpr int BT = 128;                    // tile edge (points per tile)
static constexpr int GR = D / 8;                  // 16 granules (half8) per row
static constexpr int SL = BT + 1;                 // padded row count per granule
static constexpr int MAXG = 48;                   // e-list capacity (mean 16, 8 sigma)
static constexpr int NB = N / BT;                 // 64 row/col panels
static constexpr int NSP = NB / 2;                // 32 superpanels (panel k + panel 63-k)
static constexpr int SPB = 16;                    // walker lanes per superpanel
static constexpr int GRID = 512;                  // R8/R12-proven: 2/CU, identical block mix

// Sentinels: EPAD must differ from DMASK (R9 lesson): |EPAD-DMASK| >= HALFA.
#define DMASK 3.0e38f
#define EPAD  1.0e37f

using half8    = __attribute__((ext_vector_type(8))) _Float16;
using floatx16 = __attribute__((ext_vector_type(16))) float;

__device__ __forceinline__ floatx16 zerov() { floatx16 v = {0.f}; return v; }

__device__ __forceinline__ half8 cvt8(float4 v0, float4 v1) {
    half8 h;
    h[0] = (_Float16)v0.x; h[1] = (_Float16)v0.y; h[2] = (_Float16)v0.z; h[3] = (_Float16)v0.w;
    h[4] = (_Float16)v1.x; h[5] = (_Float16)v1.y; h[6] = (_Float16)v1.z; h[7] = (_Float16)v1.w;
    return h;
}

__device__ __forceinline__ float ss8(float4 v0, float4 v1) {
    return v0.x*v0.x + v0.y*v0.y + v0.z*v0.z + v0.w*v0.w
         + v1.x*v1.x + v1.y*v1.y + v1.z*v1.z + v1.w*v1.w;
}

// Diag-first superpanel enumeration (tail-balance): idx 0 -> (k,k) diag, idx 16 ->
// (63-k,63-k) diag — BOTH cheap diagonals land on the one 5-tile lane (p=0).
// Remaining 63 idx map to off-diags: row k cols k+1..63 (63-k), then row 63-k
// cols 64-k..63 (k). Coverage: 2 + (63-k) + k = 65 tiles of superpanel k.
__device__ __forceinline__ void dec_sp2(int k, int idx, int& br, int& bc) {
    if (idx == 0)       { br = k;      bc = k;      }
    else if (idx == 16) { br = 63 - k; bc = 63 - k; }
    else {
        int j = idx - 1 - (idx > 16 ? 1 : 0);   // 0..62
        int nA = 63 - k;
        if (j < nA) { br = k;      bc = k + 1 + j; }
        else        { br = 63 - k; bc = 64 - k + (j - nA); }
    }
}

// ---- k_prep: anchors + xh (fp16) + sq + ap + GLOBAL e-lists ---------------------------
// (egrid pads are NOT initialized; k_main masks them via ecnt during the LDS copy)

__launch_bounds__(256)
__global__ void k_prep(const float* __restrict__ x, const int* __restrict__ labels,
                       _Float16* __restrict__ xh, float* __restrict__ sq,
                       int* __restrict__ anchorg, float* __restrict__ ap,
                       int* __restrict__ ecnt, float* __restrict__ egrid,
                       float* __restrict__ out) {
    __shared__ int sAnc[C];
    const int tid = threadIdx.x;
    if (blockIdx.x == 0 && tid == 0) out[0] = 0.f;
    for (int i = tid; i < C; i += 256) sAnc[i] = INT_MAX;
    __syncthreads();
    const int4* lab4 = (const int4*)labels;
    for (int t = tid; t < N / 4; t += 256) {
        int4 lv = lab4[t];
        int base = 4 * t;
        atomicMin(&sAnc[lv.x], base);
        atomicMin(&sAnc[lv.y], base + 1);
        atomicMin(&sAnc[lv.z], base + 2);
        atomicMin(&sAnc[lv.w], base + 3);
    }
    __syncthreads();
    if (tid < 2) {
        int c = blockIdx.x * 2 + tid;
        int a = sAnc[c];
        anchorg[c] = (a == INT_MAX) ? -1 : a;
    }

    const int r = blockIdx.x * 32 + (tid >> 3);
    const int sub = tid & 7;
    const float4* src = (const float4*)(x + (size_t)r * D) + sub * 4;
    half8* dst = (half8*)(xh + (size_t)r * D) + sub * 2;
    half8 hj[2];
    float ssj = 0.f;
#pragma unroll
    for (int i = 0; i < 2; ++i) {
        float4 v0 = src[2 * i], v1 = src[2 * i + 1];
        hj[i] = cvt8(v0, v1);
        dst[i] = hj[i];
        ssj += ss8(v0, v1);
    }
    ssj += __shfl_xor(ssj, 1); ssj += __shfl_xor(ssj, 2); ssj += __shfl_xor(ssj, 4);

    const int lab = labels[r];
    const int a = sAnc[lab];
    const float4* asrc = (const float4*)(x + (size_t)a * D) + sub * 4;
    float ssa = 0.f, dot = 0.f;
#pragma unroll
    for (int i = 0; i < 2; ++i) {
        float4 a0 = asrc[2 * i], a1 = asrc[2 * i + 1];
        half8 ha = cvt8(a0, a1);
        ssa += ss8(a0, a1);
#pragma unroll
        for (int e = 0; e < 8; ++e) dot = fmaf((float)ha[e], (float)hj[i][e], dot);
    }
    ssa += __shfl_xor(ssa, 1); ssa += __shfl_xor(ssa, 2); ssa += __shfl_xor(ssa, 4);
    dot += __shfl_xor(dot, 1); dot += __shfl_xor(dot, 2); dot += __shfl_xor(dot, 4);
    if (sub == 0) {
        float apv = ssa + ssj - 2.f * dot;
        sq[r] = ssj;
        ap[r] = apv;
        if (r != a) {   // append to the class e-list (anchor itself excluded)
            int slot = atomicAdd(&ecnt[lab], 1);
            if (slot < MAXG) egrid[(size_t)lab * MAXG + slot] = apv + HALFA;
        }
    }
}

// ---- k_main: R12-proven body; single delta: diag-first superpanel enumeration ---------
// (dec_sp2 puts both cheap diagonal tiles on the 5-tile lane -> drain-tail shrinks
// from +1.0 tile to ~+0.4). __launch_bounds__(512,2): proven no-spill; do NOT tighten.

__launch_bounds__(512, 2)
__global__ void k_main(const _Float16* __restrict__ xh, const int* __restrict__ labels,
                       const int* __restrict__ anchor, const float* __restrict__ sq,
                       const float* __restrict__ ap, const int* __restrict__ ecnt,
                       const float* __restrict__ egrid, float* __restrict__ out) {
    __shared__ __align__(16) _Float16 BsH[GR * SL * 8];   // 33024 B, K-major [granule][row]
    __shared__ __align__(16) float sge[64 * MAXG];        // 12288 B e-lists
    __shared__ float4 rowE[BT];
    __shared__ float4 colE[2][BT];
    __shared__ int   sArow[64];
    __shared__ float sSqA[64];
    __shared__ int   sCnt[64];
    __shared__ float wsum[8];
    half8* Bs = (half8*)BsH;

    const int tid = threadIdx.x;
    const int lane = tid & 63, w = tid >> 6;
    const int m = lane & 31, q = lane >> 5;
    const int sg = tid & 15, sr0 = tid >> 4;   // staging: granule, row base
    float local = 0.f;
    int cnt = 0;                                // hinge slots evaluated (for +h*cnt)

    const int b = blockIdx.x;
    // term1 tile coords (one tile per block: 8 class-panels x 64 j-tiles)
    const int c0 = (b >> 6) * 64, j1 = (b & 63) * BT;
    // term2 walker coords (superpanel k, lane p)
    const int kk_sp = b >> 4, p = b & 15;

    half8 af[8], breg[4];
    floatx16 acc = zerov();

    // ================= phase 0: term1 meta + EPAD-masked e-list copy + B prefetch =======
    if (tid < 64) {
        int c = c0 + tid;
        int a = anchor[c];
        int ar = (a < 0) ? 0 : a;          // dummy (absent class has cnt 0)
        sArow[tid] = ar;
        sSqA[tid] = sq[ar];
        int n = ecnt[c];
        sCnt[tid] = (n > MAXG) ? MAXG : n;
    }
    {   // e-list copy; pads (uninitialized in egrid) forced to EPAD
        const float4* srcv = (const float4*)(egrid + (size_t)c0 * MAXG);
        float4* dstv = (float4*)sge;
#pragma unroll
        for (int rep = 0; rep < 2; ++rep) {
            int idx = tid + rep * 512;
            if (idx < 64 * (MAXG / 4)) {
                int cls = idx / (MAXG / 4);
                int sb = (idx % (MAXG / 4)) * 4;
                int n = ecnt[c0 + cls]; n = (n > MAXG) ? MAXG : n;
                float4 v = srcv[idx];
                v.x = (sb + 0 < n) ? v.x : EPAD;
                v.y = (sb + 1 < n) ? v.y : EPAD;
                v.z = (sb + 2 < n) ? v.z : EPAD;
                v.w = (sb + 3 < n) ? v.w : EPAD;
                dstv[idx] = v;
            }
        }
    }
#pragma unroll
    for (int i = 0; i < 4; ++i)
        breg[i] = *((const half8*)(xh + (size_t)(j1 + sr0 + 32 * i) * D) + sg);
    if (tid < BT) {
        int j = j1 + tid;
        colE[0][tid] = make_float4(sq[j], __int_as_float(labels[j]), 0.f, 0.f);
    }
    __syncthreads();

    // ================= phase 1: term1 MFMA =================
    {   // gathered anchor rows; 2 row-groups x 4 col-groups
        int arow = sArow[(w >> 2) * 32 + m];
        const half8* aptr = (const half8*)(xh + (size_t)arow * D) + q;
#pragma unroll
        for (int k = 0; k < 8; ++k) af[k] = aptr[2 * k];
    }
#pragma unroll
    for (int i = 0; i < 4; ++i)
        Bs[sg * SL + sr0 + 32 * i] = breg[i];
    __syncthreads();

#pragma unroll
    for (int k = 0; k < 8; ++k) {
        half8 b0 = Bs[(2 * k + q) * SL + (w & 3) * 32 + m];
        acc = __builtin_amdgcn_mfma_f32_32x32x16_f16(af[k], b0, acc, 0, 0, 0);
    }

    // ================= phase 2: prefetch first term2 tile (hides under epilogue) =======
    int br0, bc0;
    dec_sp2(kk_sp, p, br0, bc0);
    {
        const half8* aptr = (const half8*)(xh + (size_t)(br0 * BT + (w >> 1) * 32 + m) * D) + q;
#pragma unroll
        for (int k = 0; k < 8; ++k) af[k] = aptr[2 * k];   // af dead after term1 MFMA
#pragma unroll
        for (int i = 0; i < 4; ++i)
            breg[i] = *((const half8*)(xh + (size_t)(bc0 * BT + sr0 + 32 * i) * D) + sg);
        if (tid < BT) {
            int i = br0 * BT + tid;
            int li = labels[i]; int a = anchor[li];
            float sqi = sq[i];
            float e2 = (i == a) ? -1e30f : ap[i] + HALFA - sqi;
            rowE[tid] = make_float4(e2, __int_as_float(li), sqi, 0.f);
        } else if (tid < 2 * BT) {
            int j = bc0 * BT + tid - BT;
            int lj = labels[j]; int a = anchor[lj];
            float sqj = sq[j];
            float e2 = (j == a) ? -1e30f : ap[j] + HALFA - sqj;
            colE[1][tid - BT] = make_float4(e2, __int_as_float(lj), sqj, 0.f);
        }
    }

    // ================= phase 3: term1 hinge epilogue =================
    __builtin_amdgcn_s_setprio(1);
    {
        float4 cj = colE[0][(w & 3) * 32 + m];
        float sqj = cj.x; int labj = __float_as_int(cj.y);
#pragma unroll
        for (int rr = 0; rr < 16; ++rr) {
            int row = (w >> 2) * 32 + (rr & 3) + 8 * (rr >> 2) + 4 * q;
            float Dv = fmaf(-2.f, acc[rr], sSqA[row] + sqj);
            Dv = (labj != c0 + row) ? Dv : DMASK;         // fold label mask into base
            int nf = (sCnt[row] + 3) & ~3;
            cnt += nf;
            for (int gb = 0; gb < nf; gb += 4) {
                float4 ev = *(const float4*)&sge[row * MAXG + gb];
                float u;
                u = ev.x - Dv; local += (__builtin_fabsf(u) < HALFA) ? u : -HALFA;
                u = ev.y - Dv; local += (__builtin_fabsf(u) < HALFA) ? u : -HALFA;
                u = ev.z - Dv; local += (__builtin_fabsf(u) < HALFA) ? u : -HALFA;
                u = ev.w - Dv; local += (__builtin_fabsf(u) < HALFA) ? u : -HALFA;
            }
        }
    }
    __builtin_amdgcn_s_setprio(0);
    __syncthreads();   // rowE/colE[1] ready; Bs free for the walker

    // ================= phase 4: term2 superpanel walker (diag-first order) =============
    {
        const int wr = w >> 1, wc = w & 1;     // 4 row-groups x 2 col-groups
        int cbuf = 1, cur_br = br0;

        for (int t = p; t < 65; t += SPB) {
            int br, bc; dec_sp2(kk_sp, t, br, bc);
            const int i0 = br * BT;
            const bool diag = (br == bc);

            if (br != cur_br) {                 // row seam: reload A panel + rowE
                cur_br = br;
                const half8* aptr = (const half8*)(xh + (size_t)(i0 + wr * 32 + m) * D) + q;
#pragma unroll
                for (int k8 = 0; k8 < 8; ++k8) af[k8] = aptr[2 * k8];
                if (tid < BT) {
                    int i = i0 + tid;
                    int li = labels[i]; int a = anchor[li];
                    float sqi = sq[i];
                    float e2 = (i == a) ? -1e30f : ap[i] + HALFA - sqi;
                    rowE[tid] = make_float4(e2, __int_as_float(li), sqi, 0.f);
                }
            }

#pragma unroll
            for (int i = 0; i < 4; ++i)
                Bs[sg * SL + sr0 + 32 * i] = breg[i];
            __syncthreads();

            if (t + SPB < 65) {                 // prefetch next tile
                int brn, bcn; dec_sp2(kk_sp, t + SPB, brn, bcn);
                int j0n = bcn * BT;
#pragma unroll
                for (int i = 0; i < 4; ++i)
                    breg[i] = *((const half8*)(xh + (size_t)(j0n + sr0 + 32 * i) * D) + sg);
                if (tid < BT) {
                    int j = j0n + tid;
                    int lj = labels[j]; int a = anchor[lj];
                    float sqj = sq[j];
                    float e2 = (j == a) ? -1e30f : ap[j] + HALFA - sqj;
                    colE[cbuf ^ 1][tid] = make_float4(e2, __int_as_float(lj), sqj, 0.f);
                }
            }

            __builtin_amdgcn_s_setprio(1);
            floatx16 acc0 = zerov(), acc1 = zerov();
#pragma unroll
            for (int k8 = 0; k8 < 8; ++k8) {
                half8 b0 = Bs[(2 * k8 + q) * SL + wc * 64 + m];
                half8 b1 = Bs[(2 * k8 + q) * SL + wc * 64 + 32 + m];
                acc0 = __builtin_amdgcn_mfma_f32_32x32x16_f16(af[k8], b0, acc0, 0, 0, 0);
                acc1 = __builtin_amdgcn_mfma_f32_32x32x16_f16(af[k8], b1, acc1, 0, 0, 0);
            }

            float sqjv[2], e2j[2]; int labj[2];
            { float4 cj = colE[cbuf][wc * 64 + m];      e2j[0] = cj.x; labj[0] = __float_as_int(cj.y); sqjv[0] = cj.z; }
            { float4 cj = colE[cbuf][wc * 64 + 32 + m]; e2j[1] = cj.x; labj[1] = __float_as_int(cj.y); sqjv[1] = cj.z; }

#pragma unroll
            for (int rr = 0; rr < 16; ++rr) {
                int row = wr * 32 + (rr & 3) + 8 * (rr >> 2) + 4 * q;
                float4 re = rowE[row];
                float e2i = re.x, sqi = re.z;
                int labi = __float_as_int(re.y);
#pragma unroll
                for (int tn = 0; tn < 2; ++tn) {
                    float dot = (tn == 0) ? acc0[rr] : acc1[rr];
                    bool ne = (labi != labj[tn]);
                    float u2 = fmaf(2.f, dot, e2i - sqjv[tn]);
                    local += (ne & (__builtin_fabsf(u2) < HALFA)) ? u2 : -HALFA;
                    if (!diag) {
                        float u2b = fmaf(2.f, dot, e2j[tn] - sqi);
                        local += (ne & (__builtin_fabsf(u2b) < HALFA)) ? u2b : -HALFA;
                    }
                }
            }
            __builtin_amdgcn_s_setprio(0);
            cnt += diag ? 32 : 64;
            cbuf ^= 1;
            __syncthreads();
        }
    }

    // compensation for the -HALFA branchless accumulation, then block reduce
    local += HALFA * (float)cnt;
#pragma unroll
    for (int off = 32; off; off >>= 1) local += __shfl_down(local, off);
    if (lane == 0) wsum[w] = local;
    __syncthreads();
    if (tid == 0) {
        float s = 0.f;
#pragma unroll
        for (int i = 0; i < 8; ++i) s += wsum[i];
        atomicAdd(out, s);
    }
}

// ---------------- launch ----------------

extern "C" void kernel_launch(void* const* d_in, const int* in_sizes, int n_in,
                              void* d_out, int out_size, void* d_ws, size_t ws_size,
                              hipStream_t stream) {
    const float* x = (const float*)d_in[0];
    const int* labels = (const int*)d_in[1];
    float* out = (float*)d_out;

    char* p = (char*)d_ws;
    int* anchor = (int*)p;        p += C * 4;
    float* sq = (float*)p;        p += N * 4;
    float* ap = (float*)p;        p += N * 4;
    int* ecnt = (int*)p;          p += C * 4;
    float* egrid = (float*)p;     p += (size_t)C * MAXG * 4;
    p = (char*)(((uintptr_t)p + 255) & ~(uintptr_t)255);
    _Float16* xh = (_Float16*)p;  // N*D*2 = 2 MB

    hipMemsetAsync(ecnt, 0, C * 4, stream);   // egrid memset not needed (masked copy)
    k_prep<<<N / 32, 256, 0, stream>>>(x, labels, xh, sq, anchor, ap, ecnt, egrid, out);
    k_main<<<GRID, 512, 0, stream>>>(xh, labels, anchor, sq, ap, ecnt, egrid, out);
}

// Round 17
// 106.802 us; speedup vs baseline: 1.7161x; 1.0288x over previous
//
#include <hip/hip_runtime.h>
#include <limits.h>
#include <stdint.h>

#define ALPHA 0.2f
#define HALFA 0.1f
static constexpr int N = 8192;
static constexpr int D = 128;
static constexpr int C = 512;
static constexpr int BT = 128;                    // tile edge (points per tile)
static constexpr int GR = D / 8;                  // 16 granules (half8) per row
static constexpr int SL = BT + 1;                 // padded row count per granule
static constexpr int MAXG = 48;                   // e-list capacity (mean 16, 8 sigma; 8-divisible)
static constexpr int NB = N / BT;                 // 64 row/col panels
static constexpr int NSP = NB / 2;                // 32 superpanels (panel k + panel 63-k)
static constexpr int SPB = 16;                    // walker lanes per superpanel
static constexpr int GRID = 512;                  // R8/R12/R14-proven: 2/CU, identical block mix

// Sentinels: EPAD must differ from DMASK (R9 lesson): |EPAD-DMASK| >= HALFA so pad
// slots never enter the band, under normal Dv or DMASK'd Dv.
#define DMASK 3.0e38f
#define EPAD  1.0e37f

using half8    = __attribute__((ext_vector_type(8))) _Float16;
using floatx16 = __attribute__((ext_vector_type(16))) float;

__device__ __forceinline__ floatx16 zerov() { floatx16 v = {0.f}; return v; }

__device__ __forceinline__ half8 cvt8(float4 v0, float4 v1) {
    half8 h;
    h[0] = (_Float16)v0.x; h[1] = (_Float16)v0.y; h[2] = (_Float16)v0.z; h[3] = (_Float16)v0.w;
    h[4] = (_Float16)v1.x; h[5] = (_Float16)v1.y; h[6] = (_Float16)v1.z; h[7] = (_Float16)v1.w;
    return h;
}

__device__ __forceinline__ float ss8(float4 v0, float4 v1) {
    return v0.x*v0.x + v0.y*v0.y + v0.z*v0.z + v0.w*v0.w
         + v1.x*v1.x + v1.y*v1.y + v1.z*v1.z + v1.w*v1.w;
}

// superpanel k: tiles 0..lenA-1 are (br=k, bc=k+t); rest are (br=63-k, bc=63-k+t-lenA)
// R12 ordering: each stride-16 lane crosses the row boundary at most once (<=1 seam).
// (R16's diag-first variant created 2-3 seams/lane and regressed 12% — do not reorder.)
__device__ __forceinline__ void dec_sp(int k, int t, int lenA, int& br, int& bc) {
    if (t < lenA) { br = k;      bc = k + t; }
    else          { br = 63 - k; bc = 63 - k + (t - lenA); }
}

// ---- k_prep: anchors + xh (fp16) + sq + ap + GLOBAL e-lists ---------------------------
// (egrid pads are NOT initialized; k_main masks them via ecnt during the LDS copy)

__launch_bounds__(256)
__global__ void k_prep(const float* __restrict__ x, const int* __restrict__ labels,
                       _Float16* __restrict__ xh, float* __restrict__ sq,
                       int* __restrict__ anchorg, float* __restrict__ ap,
                       int* __restrict__ ecnt, float* __restrict__ egrid,
                       float* __restrict__ out) {
    __shared__ int sAnc[C];
    const int tid = threadIdx.x;
    if (blockIdx.x == 0 && tid == 0) out[0] = 0.f;
    for (int i = tid; i < C; i += 256) sAnc[i] = INT_MAX;
    __syncthreads();
    const int4* lab4 = (const int4*)labels;
    for (int t = tid; t < N / 4; t += 256) {
        int4 lv = lab4[t];
        int base = 4 * t;
        atomicMin(&sAnc[lv.x], base);
        atomicMin(&sAnc[lv.y], base + 1);
        atomicMin(&sAnc[lv.z], base + 2);
        atomicMin(&sAnc[lv.w], base + 3);
    }
    __syncthreads();
    if (tid < 2) {
        int c = blockIdx.x * 2 + tid;
        int a = sAnc[c];
        anchorg[c] = (a == INT_MAX) ? -1 : a;
    }

    const int r = blockIdx.x * 32 + (tid >> 3);
    const int sub = tid & 7;
    const float4* src = (const float4*)(x + (size_t)r * D) + sub * 4;
    half8* dst = (half8*)(xh + (size_t)r * D) + sub * 2;
    half8 hj[2];
    float ssj = 0.f;
#pragma unroll
    for (int i = 0; i < 2; ++i) {
        float4 v0 = src[2 * i], v1 = src[2 * i + 1];
        hj[i] = cvt8(v0, v1);
        dst[i] = hj[i];
        ssj += ss8(v0, v1);
    }
    ssj += __shfl_xor(ssj, 1); ssj += __shfl_xor(ssj, 2); ssj += __shfl_xor(ssj, 4);

    const int lab = labels[r];
    const int a = sAnc[lab];
    const float4* asrc = (const float4*)(x + (size_t)a * D) + sub * 4;
    float ssa = 0.f, dot = 0.f;
#pragma unroll
    for (int i = 0; i < 2; ++i) {
        float4 a0 = asrc[2 * i], a1 = asrc[2 * i + 1];
        half8 ha = cvt8(a0, a1);
        ssa += ss8(a0, a1);
#pragma unroll
        for (int e = 0; e < 8; ++e) dot = fmaf((float)ha[e], (float)hj[i][e], dot);
    }
    ssa += __shfl_xor(ssa, 1); ssa += __shfl_xor(ssa, 2); ssa += __shfl_xor(ssa, 4);
    dot += __shfl_xor(dot, 1); dot += __shfl_xor(dot, 2); dot += __shfl_xor(dot, 4);
    if (sub == 0) {
        float apv = ssa + ssj - 2.f * dot;
        sq[r] = ssj;
        ap[r] = apv;
        if (r != a) {   // append to the class e-list (anchor itself excluded)
            int slot = atomicAdd(&ecnt[lab], 1);
            if (slot < MAXG) egrid[(size_t)lab * MAXG + slot] = apv + HALFA;
        }
    }
}

// ---- k_main: best-proven configuration (R14) ------------------------------------------
// 512 identical blocks (2/CU): 1 term1 tile + superpanel walker lane each; EPAD-masked
// e-list copy; branchless compensated hinges (ne folded to SALU); pipelined term1 slot
// loop; setprio around VALU-hot phases.
// __launch_bounds__(512,2): proven no-spill; do NOT tighten (R4/R6 spill disasters).

__launch_bounds__(512, 2)
__global__ void k_main(const _Float16* __restrict__ xh, const int* __restrict__ labels,
                       const int* __restrict__ anchor, const float* __restrict__ sq,
                       const float* __restrict__ ap, const int* __restrict__ ecnt,
                       const float* __restrict__ egrid, float* __restrict__ out) {
    __shared__ __align__(16) _Float16 BsH[GR * SL * 8];   // 33024 B, K-major [granule][row]
    __shared__ __align__(16) float sge[64 * MAXG];        // 12288 B e-lists
    __shared__ float4 rowE[BT];
    __shared__ float4 colE[2][BT];
    __shared__ int   sArow[64];
    __shared__ float sSqA[64];
    __shared__ int   sCnt[64];
    __shared__ float wsum[8];
    half8* Bs = (half8*)BsH;

    const int tid = threadIdx.x;
    const int lane = tid & 63, w = tid >> 6;
    const int m = lane & 31, q = lane >> 5;
    const int sg = tid & 15, sr0 = tid >> 4;   // staging: granule, row base
    float local = 0.f;
    int cnt = 0;                                // hinge slots evaluated (for +h*cnt)

    const int b = blockIdx.x;
    // term1 tile coords (one tile per block: 8 class-panels x 64 j-tiles)
    const int c0 = (b >> 6) * 64, j1 = (b & 63) * BT;
    // term2 walker coords (superpanel k, lane p)
    const int kk_sp = b >> 4, p = b & 15;
    const int lenA = 64 - kk_sp;

    half8 af[8], breg[4];
    floatx16 acc = zerov();

    // ================= phase 0: term1 meta + EPAD-masked e-list copy + B prefetch =======
    if (tid < 64) {
        int c = c0 + tid;
        int a = anchor[c];
        int ar = (a < 0) ? 0 : a;          // dummy (absent class has cnt 0)
        sArow[tid] = ar;
        sSqA[tid] = sq[ar];
        int n = ecnt[c];
        sCnt[tid] = (n > MAXG) ? MAXG : n;
    }
    {   // e-list copy; pads (uninitialized in egrid) forced to EPAD
        const float4* srcv = (const float4*)(egrid + (size_t)c0 * MAXG);
        float4* dstv = (float4*)sge;
#pragma unroll
        for (int rep = 0; rep < 2; ++rep) {
            int idx = tid + rep * 512;
            if (idx < 64 * (MAXG / 4)) {
                int cls = idx / (MAXG / 4);
                int sb = (idx % (MAXG / 4)) * 4;
                int n = ecnt[c0 + cls]; n = (n > MAXG) ? MAXG : n;
                float4 v = srcv[idx];
                v.x = (sb + 0 < n) ? v.x : EPAD;
                v.y = (sb + 1 < n) ? v.y : EPAD;
                v.z = (sb + 2 < n) ? v.z : EPAD;
                v.w = (sb + 3 < n) ? v.w : EPAD;
                dstv[idx] = v;
            }
        }
    }
#pragma unroll
    for (int i = 0; i < 4; ++i)
        breg[i] = *((const half8*)(xh + (size_t)(j1 + sr0 + 32 * i) * D) + sg);
    if (tid < BT) {
        int j = j1 + tid;
        colE[0][tid] = make_float4(sq[j], __int_as_float(labels[j]), 0.f, 0.f);
    }
    __syncthreads();

    // ================= phase 1: term1 MFMA =================
    {   // gathered anchor rows; 2 row-groups x 4 col-groups
        int arow = sArow[(w >> 2) * 32 + m];
        const half8* aptr = (const half8*)(xh + (size_t)arow * D) + q;
#pragma unroll
        for (int k = 0; k < 8; ++k) af[k] = aptr[2 * k];
    }
#pragma unroll
    for (int i = 0; i < 4; ++i)
        Bs[sg * SL + sr0 + 32 * i] = breg[i];
    __syncthreads();

#pragma unroll
    for (int k = 0; k < 8; ++k) {
        half8 b0 = Bs[(2 * k + q) * SL + (w & 3) * 32 + m];
        acc = __builtin_amdgcn_mfma_f32_32x32x16_f16(af[k], b0, acc, 0, 0, 0);
    }

    // ================= phase 2: prefetch first term2 tile (hides under epilogue) =======
    int br0, bc0;
    dec_sp(kk_sp, p, lenA, br0, bc0);
    {
        const half8* aptr = (const half8*)(xh + (size_t)(br0 * BT + (w >> 1) * 32 + m) * D) + q;
#pragma unroll
        for (int k = 0; k < 8; ++k) af[k] = aptr[2 * k];   // af dead after term1 MFMA
#pragma unroll
        for (int i = 0; i < 4; ++i)
            breg[i] = *((const half8*)(xh + (size_t)(bc0 * BT + sr0 + 32 * i) * D) + sg);
        if (tid < BT) {
            int i = br0 * BT + tid;
            int li = labels[i]; int a = anchor[li];
            float sqi = sq[i];
            float e2 = (i == a) ? -1e30f : ap[i] + HALFA - sqi;
            rowE[tid] = make_float4(e2, __int_as_float(li), sqi, 0.f);
        } else if (tid < 2 * BT) {
            int j = bc0 * BT + tid - BT;
            int lj = labels[j]; int a = anchor[lj];
            float sqj = sq[j];
            float e2 = (j == a) ? -1e30f : ap[j] + HALFA - sqj;
            colE[1][tid - BT] = make_float4(e2, __int_as_float(lj), sqj, 0.f);
        }
    }

    // ================= phase 3: term1 hinge epilogue (pipelined slot loop) =============
    __builtin_amdgcn_s_setprio(1);
    {
        float4 cj = colE[0][(w & 3) * 32 + m];
        float sqj = cj.x; int labj = __float_as_int(cj.y);
#pragma unroll
        for (int rr = 0; rr < 16; ++rr) {
            int row = (w >> 2) * 32 + (rr & 3) + 8 * (rr >> 2) + 4 * q;
            float Dv = fmaf(-2.f, acc[rr], sSqA[row] + sqj);
            Dv = (labj != c0 + row) ? Dv : DMASK;         // fold label mask into base
            int nf = (sCnt[row] + 7) & ~7;                // 8-wide; pads contribute 0
            cnt += nf;
            const float* base = &sge[row * MAXG];
            float4 e0 = *(const float4*)(base);
            float4 e1 = *(const float4*)(base + 4);
            for (int gb = 0; gb < nf; gb += 8) {
                float4 n0 = e0, n1 = e1;
                if (gb + 8 < nf) {                        // prefetch next 8 slots
                    n0 = *(const float4*)(base + gb + 8);
                    n1 = *(const float4*)(base + gb + 12);
                }
                float u;
                u = e0.x - Dv; local += (__builtin_fabsf(u) < HALFA) ? u : -HALFA;
                u = e0.y - Dv; local += (__builtin_fabsf(u) < HALFA) ? u : -HALFA;
                u = e0.z - Dv; local += (__builtin_fabsf(u) < HALFA) ? u : -HALFA;
                u = e0.w - Dv; local += (__builtin_fabsf(u) < HALFA) ? u : -HALFA;
                u = e1.x - Dv; local += (__builtin_fabsf(u) < HALFA) ? u : -HALFA;
                u = e1.y - Dv; local += (__builtin_fabsf(u) < HALFA) ? u : -HALFA;
                u = e1.z - Dv; local += (__builtin_fabsf(u) < HALFA) ? u : -HALFA;
                u = e1.w - Dv; local += (__builtin_fabsf(u) < HALFA) ? u : -HALFA;
                e0 = n0; e1 = n1;
            }
        }
    }
    __builtin_amdgcn_s_setprio(0);
    __syncthreads();   // rowE/colE[1] ready; Bs free for the walker

    // ================= phase 4: term2 superpanel walker =================
    {
        const int wr = w >> 1, wc = w & 1;     // 4 row-groups x 2 col-groups
        int cbuf = 1, cur_br = br0;

        for (int t = p; t < 65; t += SPB) {
            int br, bc; dec_sp(kk_sp, t, lenA, br, bc);
            const int i0 = br * BT;
            const bool diag = (br == bc);

            if (br != cur_br) {                 // at most one seam per block
                cur_br = br;
                const half8* aptr = (const half8*)(xh + (size_t)(i0 + wr * 32 + m) * D) + q;
#pragma unroll
                for (int k8 = 0; k8 < 8; ++k8) af[k8] = aptr[2 * k8];
                if (tid < BT) {
                    int i = i0 + tid;
                    int li = labels[i]; int a = anchor[li];
                    float sqi = sq[i];
                    float e2 = (i == a) ? -1e30f : ap[i] + HALFA - sqi;
                    rowE[tid] = make_float4(e2, __int_as_float(li), sqi, 0.f);
                }
            }

#pragma unroll
            for (int i = 0; i < 4; ++i)
                Bs[sg * SL + sr0 + 32 * i] = breg[i];
            __syncthreads();

            if (t + SPB < 65) {                 // prefetch next tile
                int brn, bcn; dec_sp(kk_sp, t + SPB, lenA, brn, bcn);
                int j0n = bcn * BT;
#pragma unroll
                for (int i = 0; i < 4; ++i)
                    breg[i] = *((const half8*)(xh + (size_t)(j0n + sr0 + 32 * i) * D) + sg);
                if (tid < BT) {
                    int j = j0n + tid;
                    int lj = labels[j]; int a = anchor[lj];
                    float sqj = sq[j];
                    float e2 = (j == a) ? -1e30f : ap[j] + HALFA - sqj;
                    colE[cbuf ^ 1][tid] = make_float4(e2, __int_as_float(lj), sqj, 0.f);
                }
            }

            __builtin_amdgcn_s_setprio(1);
            floatx16 acc0 = zerov(), acc1 = zerov();
#pragma unroll
            for (int k8 = 0; k8 < 8; ++k8) {
                half8 b0 = Bs[(2 * k8 + q) * SL + wc * 64 + m];
                half8 b1 = Bs[(2 * k8 + q) * SL + wc * 64 + 32 + m];
                acc0 = __builtin_amdgcn_mfma_f32_32x32x16_f16(af[k8], b0, acc0, 0, 0, 0);
                acc1 = __builtin_amdgcn_mfma_f32_32x32x16_f16(af[k8], b1, acc1, 0, 0, 0);
            }

            float sqjv[2], e2j[2]; int labj[2];
            { float4 cj = colE[cbuf][wc * 64 + m];      e2j[0] = cj.x; labj[0] = __float_as_int(cj.y); sqjv[0] = cj.z; }
            { float4 cj = colE[cbuf][wc * 64 + 32 + m]; e2j[1] = cj.x; labj[1] = __float_as_int(cj.y); sqjv[1] = cj.z; }

#pragma unroll
            for (int rr = 0; rr < 16; ++rr) {
                int row = wr * 32 + (rr & 3) + 8 * (rr >> 2) + 4 * q;
                float4 re = rowE[row];
                float e2i = re.x, sqi = re.z;
                int labi = __float_as_int(re.y);
#pragma unroll
                for (int tn = 0; tn < 2; ++tn) {
                    float dot = (tn == 0) ? acc0[rr] : acc1[rr];
                    bool ne = (labi != labj[tn]);
                    float u2 = fmaf(2.f, dot, e2i - sqjv[tn]);
                    local += (ne & (__builtin_fabsf(u2) < HALFA)) ? u2 : -HALFA;
                    if (!diag) {
                        float u2b = fmaf(2.f, dot, e2j[tn] - sqi);
                        local += (ne & (__builtin_fabsf(u2b) < HALFA)) ? u2b : -HALFA;
                    }
                }
            }
            __builtin_amdgcn_s_setprio(0);
            cnt += diag ? 32 : 64;
            cbuf ^= 1;
            __syncthreads();
        }
    }

    // compensation for the -HALFA branchless accumulation, then block reduce
    local += HALFA * (float)cnt;
#pragma unroll
    for (int off = 32; off; off >>= 1) local += __shfl_down(local, off);
    if (lane == 0) wsum[w] = local;
    __syncthreads();
    if (tid == 0) {
        float s = 0.f;
#pragma unroll
        for (int i = 0; i < 8; ++i) s += wsum[i];
        atomicAdd(out, s);
    }
}

// ---------------- launch ----------------

extern "C" void kernel_launch(void* const* d_in, const int* in_sizes, int n_in,
                              void* d_out, int out_size, void* d_ws, size_t ws_size,
                              hipStream_t stream) {
    const float* x = (const float*)d_in[0];
    const int* labels = (const int*)d_in[1];
    float* out = (float*)d_out;

    char* p = (char*)d_ws;
    int* anchor = (int*)p;        p += C * 4;
    float* sq = (float*)p;        p += N * 4;
    float* ap = (float*)p;        p += N * 4;
    int* ecnt = (int*)p;          p += C * 4;
    float* egrid = (float*)p;     p += (size_t)C * MAXG * 4;
    p = (char*)(((uintptr_t)p + 255) & ~(uintptr_t)255);
    _Float16* xh = (_Float16*)p;  // N*D*2 = 2 MB

    hipMemsetAsync(ecnt, 0, C * 4, stream);   // egrid memset not needed (masked copy)
    k_prep<<<N / 32, 256, 0, stream>>>(x, labels, xh, sq, anchor, ap, ecnt, egrid, out);
    k_main<<<GRID, 512, 0, stream>>>(xh, labels, anchor, sq, ap, ecnt, egrid, out);
}